// Round 14
// baseline (218.289 us; speedup 1.0000x reference)
//
#include <hip/hip_runtime.h>
#include <hip/hip_bf16.h>
#include <stdint.h>

#define C_ 64
#define WS_H1_BYTES 33554432u          // 32 MB bf16 h1
#define WKF_FRAGS 1152                 // s = (mt*2+ks)*64 + lane

typedef __bf16   bf16x8 __attribute__((ext_vector_type(8)));
typedef float    f32x4  __attribute__((ext_vector_type(4)));
typedef uint32_t u32x4  __attribute__((ext_vector_type(4)));
typedef unsigned short ush4 __attribute__((ext_vector_type(4)));
typedef unsigned short ush8 __attribute__((ext_vector_type(8)));

__device__ __forceinline__ uint32_t bf16rne(float f) {
    uint32_t u = __float_as_uint(f);
    return (u + 0x7fffu + ((u >> 16) & 1u)) >> 16;
}
__device__ __forceinline__ uint32_t packbf(float lo, float hi) {
    return bf16rne(lo) | (bf16rne(hi) << 16);
}
__device__ __forceinline__ float bf2f(uint32_t bits16) {
    return __uint_as_float(bits16 << 16);
}

// ---------------------------------------------------------------------------
// K1: conv1 via MFMA (unchanged — ~HBM roofline, ~15 us).
// ---------------------------------------------------------------------------
__global__ __launch_bounds__(256, 4) void k_conv1(const float* __restrict__ x,
                                                  const float* __restrict__ w1,
                                                  const float* __restrict__ b1,
                                                  unsigned short* __restrict__ h1) {
    __shared__ u32x4 afrag[512];
    const int t = threadIdx.x;
#pragma unroll
    for (int it = 0; it < 2; ++it) {
        int s  = it * 256 + t;
        int ln = s & 63;
        int o  = 16 * (s >> 7) + (ln & 15);
        int c0 = ((s >> 6) & 1) * 32 + (ln >> 4) * 8;
        const float* wp = w1 + o * 64 + c0;
        float4 f0 = *(const float4*)wp;
        float4 f1 = *(const float4*)(wp + 4);
        u32x4 u; u.x = packbf(f0.x, f0.y); u.y = packbf(f0.z, f0.w);
        u.z = packbf(f1.x, f1.y); u.w = packbf(f1.z, f1.w);
        afrag[s] = u;
    }
    __syncthreads();

    const int lane = t & 63, wv = t >> 6;
    const int q = lane >> 4, l15 = lane & 15;
    const int bid = blockIdx.x;
    const int b   = bid >> 8;
    const int px0 = ((bid & 255) << 8) + wv * 64;
    const size_t planeB = ((size_t)(b * C_)) << 16;

    bf16x8 A[4][2];
#pragma unroll
    for (int mt = 0; mt < 4; ++mt)
#pragma unroll
        for (int ks = 0; ks < 2; ++ks)
            A[mt][ks] = __builtin_bit_cast(bf16x8, afrag[(mt * 2 + ks) * 64 + lane]);

    float b1v[4][4];
#pragma unroll
    for (int mt = 0; mt < 4; ++mt)
#pragma unroll
        for (int r = 0; r < 4; ++r) b1v[mt][r] = b1[16 * mt + q * 4 + r];

#pragma unroll
    for (int nt = 0; nt < 4; ++nt) {
        int px = px0 + nt * 16 + l15;
        bf16x8 Bf[2];
#pragma unroll
        for (int ks = 0; ks < 2; ++ks) {
            const float* xp = x + planeB + (((size_t)(ks * 32 + q * 8)) << 16) + px;
            float v[8];
#pragma unroll
            for (int e = 0; e < 8; ++e) v[e] = xp[(size_t)e << 16];
            u32x4 u; u.x = packbf(v[0], v[1]); u.y = packbf(v[2], v[3]);
            u.z = packbf(v[4], v[5]); u.w = packbf(v[6], v[7]);
            Bf[ks] = __builtin_bit_cast(bf16x8, u);
        }
#pragma unroll
        for (int mt = 0; mt < 4; ++mt) {
            f32x4 acc = {0.f, 0.f, 0.f, 0.f};
            acc = __builtin_amdgcn_mfma_f32_16x16x32_bf16(A[mt][0], Bf[0], acc, 0, 0, 0);
            acc = __builtin_amdgcn_mfma_f32_16x16x32_bf16(A[mt][1], Bf[1], acc, 0, 0, 0);
#pragma unroll
            for (int r = 0; r < 4; ++r) {
                int o = 16 * mt + q * 4 + r;
                h1[planeB + (((size_t)o) << 16) + px] =
                    (unsigned short)bf16rne(acc[r] + b1v[mt][r]);
            }
        }
    }
}

// ---------------------------------------------------------------------------
// k_pack: pre-pack wk into bf16 MFMA A-fragments, once. Idempotent.
// ---------------------------------------------------------------------------
__global__ __launch_bounds__(256) void k_pack(const float* __restrict__ wk,
                                              u32x4* __restrict__ wkf) {
    int s = blockIdx.x * 256 + threadIdx.x;
    if (s < WKF_FRAGS) {
        int ln = s & 63;
        int kc = 16 * (s >> 7) + (ln & 15);
        int cb = ((s >> 6) & 1) * 32 + (ln >> 4) * 8;
        const float* wp = wk + kc * 64 + cb;
        float4 f0 = *(const float4*)wp;
        float4 f1 = *(const float4*)(wp + 4);
        u32x4 u; u.x = packbf(f0.x, f0.y); u.y = packbf(f0.z, f0.w);
        u.z = packbf(f1.x, f1.y); u.w = packbf(f1.z, f1.w);
        wkf[s] = u;
    }
}

// ---------------------------------------------------------------------------
// K2 = R13 phases, 2 row-adjacent tiles per block (hrow0, hrow0+1):
// staging amortized 2x; tile1's h1/x rows share 2/3 of cache lines with
// tile0 (L1-hot); Areg/wkf L1-hot for tile1. Grid 2048.
// LDS 32,960 B (4 blocks/CU = 132 KB <= 160 KB; register-capped anyway):
//   afragL : u32x4[640]        0 .. 10,240   (persistent across tiles)
//   h2p    : u32 [32][68] 10,240 .. 18,944   (inside kvt window; dead pre-D)
//   kvt    : u16[144][68] 10,240 .. 29,824   (per-tile transit)
//   w2s    : f32 [576]    29,824 .. 32,128   (persistent)
//   b2s    : f32 [64]     32,128 .. 32,384
//   bks    : f32 [144]    32,384 .. 32,960
// ---------------------------------------------------------------------------
__global__ __launch_bounds__(256, 6) void k_fused_pre(const float* __restrict__ x,
        const unsigned short* __restrict__ h1, const u32x4* __restrict__ wkf,
        const float* __restrict__ w2, const float* __restrict__ b2,
        const float* __restrict__ bk, float* __restrict__ out) {
    extern __shared__ char smem[];
    u32x4*    afragL = (u32x4*)smem;                   // [640]
    uint32_t* h2p    = (uint32_t*)(smem + 10240);      // [32][68]
    unsigned short* kvt = (unsigned short*)(smem + 10240); // [144][68]
    float* w2s = (float*)(smem + 29824);
    float* b2s = (float*)(smem + 32128);
    float* bks = (float*)(smem + 32384);

    const int t = threadIdx.x;
    int bid = blockIdx.x;
    bid = (bid & 7) * 256 + (bid >> 3);                // XCD swizzle (2048%8==0)
    const int b     = bid >> 9;
    const int rem   = bid & 511;
    const int hrow0 = (rem >> 2) << 1;                 // row pair base
    const int w0    = (rem & 3) << 6;
    const size_t planeB = ((size_t)(b * C_)) << 16;

    const int lane = t & 63, wv = t >> 6;

    // ---- Phase B thread mapping: 2 ch x 8 px ----
    const int oct  = lane & 7;
    const int cpw  = lane >> 3;
    const int cpb  = wv * 8 + cpw;
    const int cB0  = cpb * 2;
    const int pxB  = oct << 3;
    const int gxB  = w0 + pxB;
    const bool beL = (oct == 0);
    const bool beR = (oct == 7);
    const bool beact = beL | beR;
    const int   bgxm = (gxB == 0) ? 0 : gxB - 1;
    const float bmL  = (gxB == 0) ? 0.f : 1.f;
    const int   bgxp = (gxB + 8 > 255) ? 255 : gxB + 8;
    const float bmR  = (gxB + 8 > 255) ? 0.f : 1.f;
    const int   beoff = beL ? bgxm : bgxp;

    // ---- Phase C/D/E thread mapping: 4 ch x 4 px ----
    const int csub = lane >> 4, pg = lane & 15;
    const int px0l = pg << 2;
    const int gx0  = w0 + px0l;
    const int c0   = wv * 16 + csub * 4;
    const bool eL  = (pg == 0);
    const bool eR  = (pg == 15);
    const bool eact = eL | eR;
    const int   gxm = (gx0 == 0) ? 0 : gx0 - 1;
    const float mL  = (gx0 == 0) ? 0.f : 1.f;
    const int   gxp = (gx0 + 4 > 255) ? 255 : gx0 + 4;
    const float mR  = (gx0 + 4 > 255) ? 0.f : 1.f;
    const int   eoff = eL ? gxm : gxp;

    // ---- prefetch tile0 h1 taps (hidden under staging) ----
    ush8 hq[6]; unsigned short hev[6];
    {
        int gofs0[3];
#pragma unroll
        for (int dy = 0; dy < 3; ++dy) {
            int gy = hrow0 + dy - 1;
            int gyc = gy < 0 ? 0 : (gy > 255 ? 255 : gy);
            gofs0[dy] = gyc << 8;
        }
#pragma unroll
        for (int cc = 0; cc < 2; ++cc) {
            const unsigned short* hc = h1 + planeB + ((size_t)(cB0 + cc) << 16);
#pragma unroll
            for (int dy = 0; dy < 3; ++dy) {
                const unsigned short* hr = hc + gofs0[dy];
                hq[cc * 3 + dy] = *(const ush8*)(hr + gxB);
                if (beact) hev[cc * 3 + dy] = hr[beoff];
            }
        }
    }

    // ---- Phase A: stage afragL + weights (once per block) ----
#pragma unroll
    for (int it = 0; it < 3; ++it) {
        int s = it * 256 + t;
        if (s < 640) afragL[s] = wkf[s];
    }
#pragma unroll
    for (int it = 0; it < 3; ++it) {
        int s = it * 256 + t;
        if (s < 576) w2s[s] = w2[s];
    }
    if (t < 64)  b2s[t] = b2[t];
    if (t < 144) bks[t] = bk[t];
    __syncthreads();

    // ---- tile loop: hrow0, hrow0+1 ----
    for (int tt = 0; tt < 2; ++tt) {
        const int hrow = hrow0 + tt;
        bool rowok[3]; int gofs[3];
#pragma unroll
        for (int dy = 0; dy < 3; ++dy) {
            int gy = hrow + dy - 1;
            rowok[dy] = ((unsigned)gy < 256u);
            int gyc = gy < 0 ? 0 : (gy > 255 ? 255 : gy);
            gofs[dy] = gyc << 8;
        }

        if (tt == 1) {
            __syncthreads();                           // tile0 E done; reuse LDS
#pragma unroll
            for (int cc = 0; cc < 2; ++cc) {           // 2/3 rows L1-hot
                const unsigned short* hc = h1 + planeB + ((size_t)(cB0 + cc) << 16);
#pragma unroll
                for (int dy = 0; dy < 3; ++dy) {
                    const unsigned short* hr = hc + gofs[dy];
                    hq[cc * 3 + dy] = *(const ush8*)(hr + gxB);
                    if (beact) hev[cc * 3 + dy] = hr[beoff];
                }
            }
        }

        // ---- Phase B: dw 3x3, 2 ch x 8 px; shuffled edges ----
        float a[2][8];
#pragma unroll
        for (int cc = 0; cc < 2; ++cc) {
            int c = cB0 + cc;
            float bv = b2s[c];
#pragma unroll
            for (int p = 0; p < 8; ++p) a[cc][p] = bv;
#pragma unroll
            for (int dy = 0; dy < 3; ++dy) {
                ush8 v = hq[cc * 3 + dy];
                float f[8];
#pragma unroll
                for (int p = 0; p < 8; ++p) f[p] = bf2f(v[p]);
                float fmI = __shfl_up(f[7], 1);
                float fpI = __shfl_down(f[0], 1);
                if (rowok[dy]) {
                    float in[10];
                    in[0] = beL ? bf2f(hev[cc * 3 + dy]) * bmL : fmI;
#pragma unroll
                    for (int p = 0; p < 8; ++p) in[p + 1] = f[p];
                    in[9] = beR ? bf2f(hev[cc * 3 + dy]) * bmR : fpI;
                    float wL = w2s[c * 9 + dy * 3 + 0];
                    float wC = w2s[c * 9 + dy * 3 + 1];
                    float wR = w2s[c * 9 + dy * 3 + 2];
#pragma unroll
                    for (int p = 0; p < 8; ++p)
                        a[cc][p] = fmaf(in[p], wL,
                                   fmaf(in[p + 1], wC,
                                   fmaf(in[p + 2], wR, a[cc][p])));
                }
            }
        }
        {
            u32x4 u0, u1;
#pragma unroll
            for (int p = 0; p < 4; ++p) {
                u0[p] = packbf(a[0][p],     a[1][p]);
                u1[p] = packbf(a[0][p + 4], a[1][p + 4]);
            }
            *(u32x4*)&h2p[cpb * 68 + pxB]     = u0;
            *(u32x4*)&h2p[cpb * 68 + pxB + 4] = u1;
        }
        __syncthreads();

        // ---- Phase C: MFMA. mt0-4 LDS; mt5-8 from wkf (L1-hot tile1) ----
        const int q = lane >> 4, l15 = lane & 15;
        const int pxr = wv * 16 + l15;
        u32x4 Areg[8];
#pragma unroll
        for (int f = 0; f < 8; ++f) Areg[f] = wkf[640 + f * 64 + lane];
        bf16x8 Bf[2];
#pragma unroll
        for (int ks = 0; ks < 2; ++ks) {
            u32x4 u;
#pragma unroll
            for (int j = 0; j < 4; ++j)
                u[j] = h2p[(ks * 16 + q * 4 + j) * 68 + pxr];
            Bf[ks] = __builtin_bit_cast(bf16x8, u);
        }
        f32x4 acc[9];
#pragma unroll
        for (int mt = 0; mt < 9; ++mt) acc[mt] = (f32x4){0.f, 0.f, 0.f, 0.f};
#pragma unroll
        for (int mt = 0; mt < 5; ++mt) {
            bf16x8 a0 = __builtin_bit_cast(bf16x8, afragL[(mt * 2 + 0) * 64 + lane]);
            acc[mt] = __builtin_amdgcn_mfma_f32_16x16x32_bf16(a0, Bf[0], acc[mt], 0, 0, 0);
            bf16x8 a1 = __builtin_bit_cast(bf16x8, afragL[(mt * 2 + 1) * 64 + lane]);
            acc[mt] = __builtin_amdgcn_mfma_f32_16x16x32_bf16(a1, Bf[1], acc[mt], 0, 0, 0);
        }
#pragma unroll
        for (int mt = 5; mt < 9; ++mt) {
            acc[mt] = __builtin_amdgcn_mfma_f32_16x16x32_bf16(
                __builtin_bit_cast(bf16x8, Areg[(mt - 5) * 2 + 0]), Bf[0], acc[mt], 0, 0, 0);
            acc[mt] = __builtin_amdgcn_mfma_f32_16x16x32_bf16(
                __builtin_bit_cast(bf16x8, Areg[(mt - 5) * 2 + 1]), Bf[1], acc[mt], 0, 0, 0);
        }
        __syncthreads();                               // h2p reads done

        // ---- Phase D: kv + bk -> kvt; prefetch x taps for cc=0 ----
        float4 xq[2][3]; float xev[2][3];
        {
            const float* xc = x + planeB + ((size_t)c0 << 16);
#pragma unroll
            for (int dy = 0; dy < 3; ++dy) {
                const float* xr = xc + gofs[dy];
                xq[0][dy] = *(const float4*)(xr + gx0);
                if (eact) xev[0][dy] = xr[eoff];
            }
        }
#pragma unroll
        for (int mt = 0; mt < 9; ++mt) {
            int kc0 = 16 * mt + q * 4;
#pragma unroll
            for (int r = 0; r < 4; ++r) {
                float v = acc[mt][r] + bks[kc0 + r];
                kvt[(kc0 + r) * 68 + pxr] = (unsigned short)bf16rne(v);
            }
        }
        __syncthreads();

        // ---- Phase E: apply; x loads rotated one cc ahead ----
#pragma unroll
        for (int cc = 0; cc < 4; ++cc) {
            if (cc < 3) {
                const float* xc = x + planeB + ((size_t)(c0 + cc + 1) << 16);
#pragma unroll
                for (int dy = 0; dy < 3; ++dy) {
                    const float* xr = xc + gofs[dy];
                    xq[(cc + 1) & 1][dy] = *(const float4*)(xr + gx0);
                    if (eact) xev[(cc + 1) & 1][dy] = xr[eoff];
                }
            }
            int c  = c0 + cc;
            int r0 = (9 * c) >> 2;                     // (9c)&3 == cc
            ush4 kr0 = *(const ush4*)&kvt[(r0 + 0) * 68 + px0l];
            ush4 kr1 = *(const ush4*)&kvt[(r0 + 1) * 68 + px0l];
            ush4 kr2 = *(const ush4*)&kvt[(r0 + 2) * 68 + px0l];
            float kvf[3][4];
#pragma unroll
            for (int p = 0; p < 4; ++p) {
                kvf[0][p] = bf2f(kr0[p]);
                kvf[1][p] = bf2f(kr1[p]);
                kvf[2][p] = bf2f(kr2[p]);
            }
            float o[4] = {0.f, 0.f, 0.f, 0.f};
#pragma unroll
            for (int dy = 0; dy < 3; ++dy) {
                float4 xv = xq[cc & 1][dy];
                float inI0 = __shfl_up(xv.w, 1);
                float inI5 = __shfl_down(xv.x, 1);
                if (rowok[dy]) {
                    float in[6];
                    in[0] = eL ? xev[cc & 1][dy] * mL : inI0;
                    in[1] = xv.x; in[2] = xv.y; in[3] = xv.z; in[4] = xv.w;
                    in[5] = eR ? xev[cc & 1][dy] * mR : inI5;
#pragma unroll
                    for (int tx = 0; tx < 3; ++tx) {
#pragma unroll
                        for (int p = 0; p < 4; ++p)
                            o[p] = fmaf(in[p + tx],
                                        kvf[(cc + dy * 3 + tx) >> 2][p], o[p]);
                    }
                }
            }
            float4 o4 = {o[0], o[1], o[2], o[3]};
            *(float4*)(out + planeB + ((size_t)c << 16) + (hrow << 8) + gx0) = o4;
        }
    }
}

// ---------------------------------------------------------------------------
// Fallback (ws too small for wkf): R6-style kernel. LDS 30,272 B.
// ---------------------------------------------------------------------------
__global__ __launch_bounds__(256, 5) void k_fused_fb(const float* __restrict__ x,
        const unsigned short* __restrict__ h1,
        const float* __restrict__ w2, const float* __restrict__ b2,
        const float* __restrict__ wk, const float* __restrict__ bk,
        float* __restrict__ out) {
    extern __shared__ char smem[];
    u32x4*    afrag = (u32x4*)smem;
    uint32_t* h2p   = (uint32_t*)(smem + 18432);
    float*    w2s   = (float*)(smem + 27136);
    float*    b2s   = (float*)(smem + 29440);
    float*    bks   = (float*)(smem + 29696);
    unsigned short* kvt = (unsigned short*)smem;

    const int t = threadIdx.x;
    int bid = blockIdx.x;
    bid = (bid & 7) * 512 + (bid >> 3);
    const int b    = bid >> 10;
    const int rem  = bid & 1023;
    const int hrow = rem >> 2;
    const int w0   = (rem & 3) << 6;
    const size_t planeB = ((size_t)(b * C_)) << 16;

    const int lane = t & 63, wv = t >> 6;
    const int csub = lane >> 4, pg = lane & 15;
    const int px0l = pg << 2;
    const int gx0  = w0 + px0l;
    const int c0   = wv * 16 + csub * 4;

    const int   gxm = (gx0 == 0) ? 0 : gx0 - 1;
    const float mL  = (gx0 == 0) ? 0.f : 1.f;
    const int   gxp = (gx0 + 4 > 255) ? 255 : gx0 + 4;
    const float mR  = (gx0 + 4 > 255) ? 0.f : 1.f;

    bool rowok[3]; int gofs[3];
#pragma unroll
    for (int dy = 0; dy < 3; ++dy) {
        int gy = hrow + dy - 1;
        rowok[dy] = ((unsigned)gy < 256u);
        int gyc = gy < 0 ? 0 : (gy > 255 ? 255 : gy);
        gofs[dy] = gyc << 8;
    }

#pragma unroll
    for (int it = 0; it < 5; ++it) {
        int s = it * 256 + t;
        if (s < 1152) {
            int ln = s & 63;
            int kc = 16 * (s >> 7) + (ln & 15);
            int cb = ((s >> 6) & 1) * 32 + (ln >> 4) * 8;
            const float* wp = wk + kc * 64 + cb;
            float4 f0 = *(const float4*)wp;
            float4 f1 = *(const float4*)(wp + 4);
            u32x4 u; u.x = packbf(f0.x, f0.y); u.y = packbf(f0.z, f0.w);
            u.z = packbf(f1.x, f1.y); u.w = packbf(f1.z, f1.w);
            afrag[s] = u;
        }
    }
#pragma unroll
    for (int it = 0; it < 3; ++it) {
        int s = it * 256 + t;
        if (s < 576) w2s[s] = w2[s];
    }
    if (t < 64)  b2s[t] = b2[t];
    if (t < 144) bks[t] = bk[t];
    __syncthreads();

    float ah[4][4];
#pragma unroll
    for (int cc = 0; cc < 4; ++cc) {
        int c = c0 + cc;
        const unsigned short* hc = h1 + planeB + ((size_t)c << 16);
        float bv = b2s[c];
        float a0 = bv, a1 = bv, a2 = bv, a3 = bv;
#pragma unroll
        for (int dy = 0; dy < 3; ++dy) {
            if (rowok[dy]) {
                const unsigned short* hr = hc + gofs[dy];
                ush4 v = *(const ush4*)(hr + gx0);
                float f0 = bf2f(v[0]), f1 = bf2f(v[1]);
                float f2 = bf2f(v[2]), f3 = bf2f(v[3]);
                float fm = bf2f(hr[gxm]) * mL;
                float fp = bf2f(hr[gxp]) * mR;
                float wL = w2s[c * 9 + dy * 3 + 0];
                float wC = w2s[c * 9 + dy * 3 + 1];
                float wR = w2s[c * 9 + dy * 3 + 2];
                a0 = fmaf(fm, wL, fmaf(f0, wC, fmaf(f1, wR, a0)));
                a1 = fmaf(f0, wL, fmaf(f1, wC, fmaf(f2, wR, a1)));
                a2 = fmaf(f1, wL, fmaf(f2, wC, fmaf(f3, wR, a2)));
                a3 = fmaf(f2, wL, fmaf(f3, wC, fmaf(fp, wR, a3)));
            }
        }
        ah[cc][0] = a0; ah[cc][1] = a1; ah[cc][2] = a2; ah[cc][3] = a3;
    }
    {
        int cpb = c0 >> 1;
        u32x4 u0, u1;
#pragma unroll
        for (int p = 0; p < 4; ++p) {
            u0[p] = packbf(ah[0][p], ah[1][p]);
            u1[p] = packbf(ah[2][p], ah[3][p]);
        }
        *(u32x4*)&h2p[(cpb + 0) * 68 + px0l] = u0;
        *(u32x4*)&h2p[(cpb + 1) * 68 + px0l] = u1;
    }
    __syncthreads();

    const int q = lane >> 4, l15 = lane & 15;
    const int pxr = wv * 16 + l15;
    bf16x8 Bf[2];
#pragma unroll
    for (int ks = 0; ks < 2; ++ks) {
        u32x4 u;
#pragma unroll
        for (int j = 0; j < 4; ++j)
            u[j] = h2p[(ks * 16 + q * 4 + j) * 68 + pxr];
        Bf[ks] = __builtin_bit_cast(bf16x8, u);
    }
    f32x4 acc[9];
#pragma unroll
    for (int mt = 0; mt < 9; ++mt) acc[mt] = (f32x4){0.f, 0.f, 0.f, 0.f};
#pragma unroll
    for (int mt = 0; mt < 9; ++mt) {
        bf16x8 a0 = __builtin_bit_cast(bf16x8, afrag[(mt * 2 + 0) * 64 + lane]);
        acc[mt] = __builtin_amdgcn_mfma_f32_16x16x32_bf16(a0, Bf[0], acc[mt], 0, 0, 0);
        bf16x8 a1 = __builtin_bit_cast(bf16x8, afrag[(mt * 2 + 1) * 64 + lane]);
        acc[mt] = __builtin_amdgcn_mfma_f32_16x16x32_bf16(a1, Bf[1], acc[mt], 0, 0, 0);
    }
    __syncthreads();

#pragma unroll
    for (int mt = 0; mt < 9; ++mt) {
        int kc0 = 16 * mt + q * 4;
#pragma unroll
        for (int r = 0; r < 4; ++r) {
            float v = acc[mt][r] + bks[kc0 + r];
            kvt[(kc0 + r) * 68 + pxr] = (unsigned short)bf16rne(v);
        }
    }
    __syncthreads();

#pragma unroll
    for (int cc = 0; cc < 4; ++cc) {
        int c  = c0 + cc;
        int r0 = (9 * c) >> 2;
        ush4 kr0 = *(const ush4*)&kvt[(r0 + 0) * 68 + px0l];
        ush4 kr1 = *(const ush4*)&kvt[(r0 + 1) * 68 + px0l];
        ush4 kr2 = *(const ush4*)&kvt[(r0 + 2) * 68 + px0l];
        float kvf[3][4];
#pragma unroll
        for (int p = 0; p < 4; ++p) {
            kvf[0][p] = bf2f(kr0[p]);
            kvf[1][p] = bf2f(kr1[p]);
            kvf[2][p] = bf2f(kr2[p]);
        }
        const float* xc = x + planeB + ((size_t)c << 16);
        float o[4] = {0.f, 0.f, 0.f, 0.f};
#pragma unroll
        for (int dy = 0; dy < 3; ++dy) {
            if (rowok[dy]) {
                const float* xr = xc + gofs[dy];
                float4 xv = *(const float4*)(xr + gx0);
                float in[6];
                in[0] = xr[gxm] * mL;
                in[1] = xv.x; in[2] = xv.y; in[3] = xv.z; in[4] = xv.w;
                in[5] = xr[gxp] * mR;
#pragma unroll
                for (int tx = 0; tx < 3; ++tx) {
#pragma unroll
                    for (int p = 0; p < 4; ++p)
                        o[p] = fmaf(in[p + tx],
                                    kvf[(cc + dy * 3 + tx) >> 2][p], o[p]);
                }
            }
        }
        float4 o4 = {o[0], o[1], o[2], o[3]};
        *(float4*)(out + planeB + ((size_t)c << 16) + (hrow << 8) + gx0) = o4;
    }
}

// ---------------------------------------------------------------------------
extern "C" void kernel_launch(void* const* d_in, const int* in_sizes, int n_in,
                              void* d_out, int out_size, void* d_ws, size_t ws_size,
                              hipStream_t stream) {
    const float* x  = (const float*)d_in[0];
    const float* w1 = (const float*)d_in[1];
    const float* b1 = (const float*)d_in[2];
    const float* w2 = (const float*)d_in[3];
    const float* b2 = (const float*)d_in[4];
    const float* wk = (const float*)d_in[5];
    const float* bk = (const float*)d_in[6];
    float* out = (float*)d_out;
    unsigned short* h1 = (unsigned short*)d_ws;      // 32 MB bf16

    const size_t need = (size_t)WS_H1_BYTES + WKF_FRAGS * sizeof(u32x4);
    if (ws_size >= need) {
        u32x4* wkf = (u32x4*)((char*)d_ws + WS_H1_BYTES);
        k_pack<<<(WKF_FRAGS + 255) / 256, 256, 0, stream>>>(wk, wkf);
        k_conv1<<<1024, 256, 0, stream>>>(x, w1, b1, h1);
        k_fused_pre<<<2048, 256, 32960, stream>>>(x, h1, wkf, w2, b2, bk, out);
    } else {
        k_conv1<<<1024, 256, 0, stream>>>(x, w1, b1, h1);
        k_fused_fb<<<4096, 256, 30272, stream>>>(x, h1, w2, b2, wk, bk, out);
    }
}

// Round 15
// 115.085 us; speedup vs baseline: 1.8968x; 1.8968x over previous
//
#include <hip/hip_runtime.h>
#include <hip/hip_bf16.h>
#include <stdint.h>

#define C_ 64
#define WS_H1_BYTES 33554432u          // 32 MB bf16 h1
#define WKF_FRAGS 1152                 // s = (mt*2+ks)*64 + lane

typedef __bf16   bf16x8 __attribute__((ext_vector_type(8)));
typedef float    f32x4  __attribute__((ext_vector_type(4)));
typedef uint32_t u32x4  __attribute__((ext_vector_type(4)));
typedef unsigned short ush4 __attribute__((ext_vector_type(4)));
typedef unsigned short ush8 __attribute__((ext_vector_type(8)));

__device__ __forceinline__ uint32_t bf16rne(float f) {
    uint32_t u = __float_as_uint(f);
    return (u + 0x7fffu + ((u >> 16) & 1u)) >> 16;
}
__device__ __forceinline__ uint32_t packbf(float lo, float hi) {
    return bf16rne(lo) | (bf16rne(hi) << 16);
}
__device__ __forceinline__ float bf2f(uint32_t bits16) {
    return __uint_as_float(bits16 << 16);
}

// ---------------------------------------------------------------------------
// K1: conv1 via MFMA (unchanged — ~HBM roofline, ~15 us).
// ---------------------------------------------------------------------------
__global__ __launch_bounds__(256, 4) void k_conv1(const float* __restrict__ x,
                                                  const float* __restrict__ w1,
                                                  const float* __restrict__ b1,
                                                  unsigned short* __restrict__ h1) {
    __shared__ u32x4 afrag[512];
    const int t = threadIdx.x;
#pragma unroll
    for (int it = 0; it < 2; ++it) {
        int s  = it * 256 + t;
        int ln = s & 63;
        int o  = 16 * (s >> 7) + (ln & 15);
        int c0 = ((s >> 6) & 1) * 32 + (ln >> 4) * 8;
        const float* wp = w1 + o * 64 + c0;
        float4 f0 = *(const float4*)wp;
        float4 f1 = *(const float4*)(wp + 4);
        u32x4 u; u.x = packbf(f0.x, f0.y); u.y = packbf(f0.z, f0.w);
        u.z = packbf(f1.x, f1.y); u.w = packbf(f1.z, f1.w);
        afrag[s] = u;
    }
    __syncthreads();

    const int lane = t & 63, wv = t >> 6;
    const int q = lane >> 4, l15 = lane & 15;
    const int bid = blockIdx.x;
    const int b   = bid >> 8;
    const int px0 = ((bid & 255) << 8) + wv * 64;
    const size_t planeB = ((size_t)(b * C_)) << 16;

    bf16x8 A[4][2];
#pragma unroll
    for (int mt = 0; mt < 4; ++mt)
#pragma unroll
        for (int ks = 0; ks < 2; ++ks)
            A[mt][ks] = __builtin_bit_cast(bf16x8, afrag[(mt * 2 + ks) * 64 + lane]);

    float b1v[4][4];
#pragma unroll
    for (int mt = 0; mt < 4; ++mt)
#pragma unroll
        for (int r = 0; r < 4; ++r) b1v[mt][r] = b1[16 * mt + q * 4 + r];

#pragma unroll
    for (int nt = 0; nt < 4; ++nt) {
        int px = px0 + nt * 16 + l15;
        bf16x8 Bf[2];
#pragma unroll
        for (int ks = 0; ks < 2; ++ks) {
            const float* xp = x + planeB + (((size_t)(ks * 32 + q * 8)) << 16) + px;
            float v[8];
#pragma unroll
            for (int e = 0; e < 8; ++e) v[e] = xp[(size_t)e << 16];
            u32x4 u; u.x = packbf(v[0], v[1]); u.y = packbf(v[2], v[3]);
            u.z = packbf(v[4], v[5]); u.w = packbf(v[6], v[7]);
            Bf[ks] = __builtin_bit_cast(bf16x8, u);
        }
#pragma unroll
        for (int mt = 0; mt < 4; ++mt) {
            f32x4 acc = {0.f, 0.f, 0.f, 0.f};
            acc = __builtin_amdgcn_mfma_f32_16x16x32_bf16(A[mt][0], Bf[0], acc, 0, 0, 0);
            acc = __builtin_amdgcn_mfma_f32_16x16x32_bf16(A[mt][1], Bf[1], acc, 0, 0, 0);
#pragma unroll
            for (int r = 0; r < 4; ++r) {
                int o = 16 * mt + q * 4 + r;
                h1[planeB + (((size_t)o) << 16) + px] =
                    (unsigned short)bf16rne(acc[r] + b1v[mt][r]);
            }
        }
    }
}

// ---------------------------------------------------------------------------
// k_pack: pre-pack wk into bf16 MFMA A-fragments, once. Idempotent.
// ---------------------------------------------------------------------------
__global__ __launch_bounds__(256) void k_pack(const float* __restrict__ wk,
                                              u32x4* __restrict__ wkf) {
    int s = blockIdx.x * 256 + threadIdx.x;
    if (s < WKF_FRAGS) {
        int ln = s & 63;
        int kc = 16 * (s >> 7) + (ln & 15);
        int cb = ((s >> 6) & 1) * 32 + (ln >> 4) * 8;
        const float* wp = wk + kc * 64 + cb;
        float4 f0 = *(const float4*)wp;
        float4 f1 = *(const float4*)(wp + 4);
        u32x4 u; u.x = packbf(f0.x, f0.y); u.y = packbf(f0.z, f0.w);
        u.z = packbf(f1.x, f1.y); u.w = packbf(f1.z, f1.w);
        wkf[s] = u;
    }
}

// ---------------------------------------------------------------------------
// K2 = R14 row-pair structure with a FEASIBLE resource envelope:
// __launch_bounds__(256,4) -> 128 reg/thread budget (no spill; R13's live
// set ~76 fits with slack) and 4 x 32,960 B LDS = 132 KB <= 160 KB.
// 2 row-adjacent tiles per block: staging amortized 2x, h1/x rows 2/3
// L1-hot for tile1, Areg/wkf L1-hot. Grid 2048.
// LDS layout:
//   afragL : u32x4[640]        0 .. 10,240   (persistent across tiles)
//   h2p    : u32 [32][68] 10,240 .. 18,944   (inside kvt window; dead pre-D)
//   kvt    : u16[144][68] 10,240 .. 29,824   (per-tile transit)
//   w2s    : f32 [576]    29,824 .. 32,128   (persistent)
//   b2s/bks               32,128 .. 32,960
// ---------------------------------------------------------------------------
__global__ __launch_bounds__(256, 4) void k_fused_pre(const float* __restrict__ x,
        const unsigned short* __restrict__ h1, const u32x4* __restrict__ wkf,
        const float* __restrict__ w2, const float* __restrict__ b2,
        const float* __restrict__ bk, float* __restrict__ out) {
    extern __shared__ char smem[];
    u32x4*    afragL = (u32x4*)smem;                   // [640]
    uint32_t* h2p    = (uint32_t*)(smem + 10240);      // [32][68]
    unsigned short* kvt = (unsigned short*)(smem + 10240); // [144][68]
    float* w2s = (float*)(smem + 29824);
    float* b2s = (float*)(smem + 32128);
    float* bks = (float*)(smem + 32384);

    const int t = threadIdx.x;
    int bid = blockIdx.x;
    bid = (bid & 7) * 256 + (bid >> 3);                // XCD swizzle (2048%8==0)
    const int b     = bid >> 9;
    const int rem   = bid & 511;
    const int hrow0 = (rem >> 2) << 1;                 // row pair base
    const int w0    = (rem & 3) << 6;
    const size_t planeB = ((size_t)(b * C_)) << 16;

    const int lane = t & 63, wv = t >> 6;

    // ---- Phase B thread mapping: 2 ch x 8 px ----
    const int oct  = lane & 7;
    const int cpw  = lane >> 3;
    const int cpb  = wv * 8 + cpw;
    const int cB0  = cpb * 2;
    const int pxB  = oct << 3;
    const int gxB  = w0 + pxB;
    const bool beL = (oct == 0);
    const bool beR = (oct == 7);
    const bool beact = beL | beR;
    const int   bgxm = (gxB == 0) ? 0 : gxB - 1;
    const float bmL  = (gxB == 0) ? 0.f : 1.f;
    const int   bgxp = (gxB + 8 > 255) ? 255 : gxB + 8;
    const float bmR  = (gxB + 8 > 255) ? 0.f : 1.f;
    const int   beoff = beL ? bgxm : bgxp;

    // ---- Phase C/D/E thread mapping: 4 ch x 4 px ----
    const int csub = lane >> 4, pg = lane & 15;
    const int px0l = pg << 2;
    const int gx0  = w0 + px0l;
    const int c0   = wv * 16 + csub * 4;
    const bool eL  = (pg == 0);
    const bool eR  = (pg == 15);
    const bool eact = eL | eR;
    const int   gxm = (gx0 == 0) ? 0 : gx0 - 1;
    const float mL  = (gx0 == 0) ? 0.f : 1.f;
    const int   gxp = (gx0 + 4 > 255) ? 255 : gx0 + 4;
    const float mR  = (gx0 + 4 > 255) ? 0.f : 1.f;
    const int   eoff = eL ? gxm : gxp;

    // ---- Phase A: stage afragL + weights (once per block) ----
#pragma unroll
    for (int it = 0; it < 3; ++it) {
        int s = it * 256 + t;
        if (s < 640) afragL[s] = wkf[s];
    }
#pragma unroll
    for (int it = 0; it < 3; ++it) {
        int s = it * 256 + t;
        if (s < 576) w2s[s] = w2[s];
    }
    if (t < 64)  b2s[t] = b2[t];
    if (t < 144) bks[t] = bk[t];
    __syncthreads();

    // ---- tile loop: hrow0, hrow0+1 ----
    for (int tt = 0; tt < 2; ++tt) {
        const int hrow = hrow0 + tt;
        bool rowok[3]; int gofs[3];
#pragma unroll
        for (int dy = 0; dy < 3; ++dy) {
            int gy = hrow + dy - 1;
            rowok[dy] = ((unsigned)gy < 256u);
            int gyc = gy < 0 ? 0 : (gy > 255 ? 255 : gy);
            gofs[dy] = gyc << 8;
        }

        if (tt == 1) __syncthreads();                  // tile0 E done; reuse LDS

        // ---- Phase B: h1 taps (tile1: 2/3 rows L1-hot) + dw 3x3 ----
        ush8 hq[6]; unsigned short hev[6];
#pragma unroll
        for (int cc = 0; cc < 2; ++cc) {
            const unsigned short* hc = h1 + planeB + ((size_t)(cB0 + cc) << 16);
#pragma unroll
            for (int dy = 0; dy < 3; ++dy) {
                const unsigned short* hr = hc + gofs[dy];
                hq[cc * 3 + dy] = *(const ush8*)(hr + gxB);
                if (beact) hev[cc * 3 + dy] = hr[beoff];
            }
        }
        float a[2][8];
#pragma unroll
        for (int cc = 0; cc < 2; ++cc) {
            int c = cB0 + cc;
            float bv = b2s[c];
#pragma unroll
            for (int p = 0; p < 8; ++p) a[cc][p] = bv;
#pragma unroll
            for (int dy = 0; dy < 3; ++dy) {
                ush8 v = hq[cc * 3 + dy];
                float f[8];
#pragma unroll
                for (int p = 0; p < 8; ++p) f[p] = bf2f(v[p]);
                float fmI = __shfl_up(f[7], 1);
                float fpI = __shfl_down(f[0], 1);
                if (rowok[dy]) {
                    float in[10];
                    in[0] = beL ? bf2f(hev[cc * 3 + dy]) * bmL : fmI;
#pragma unroll
                    for (int p = 0; p < 8; ++p) in[p + 1] = f[p];
                    in[9] = beR ? bf2f(hev[cc * 3 + dy]) * bmR : fpI;
                    float wL = w2s[c * 9 + dy * 3 + 0];
                    float wC = w2s[c * 9 + dy * 3 + 1];
                    float wR = w2s[c * 9 + dy * 3 + 2];
#pragma unroll
                    for (int p = 0; p < 8; ++p)
                        a[cc][p] = fmaf(in[p], wL,
                                   fmaf(in[p + 1], wC,
                                   fmaf(in[p + 2], wR, a[cc][p])));
                }
            }
        }
        {
            u32x4 u0, u1;
#pragma unroll
            for (int p = 0; p < 4; ++p) {
                u0[p] = packbf(a[0][p],     a[1][p]);
                u1[p] = packbf(a[0][p + 4], a[1][p + 4]);
            }
            *(u32x4*)&h2p[cpb * 68 + pxB]     = u0;
            *(u32x4*)&h2p[cpb * 68 + pxB + 4] = u1;
        }
        __syncthreads();

        // ---- Phase C: MFMA. mt0-4 LDS; mt5-8 from wkf (L1-hot tile1) ----
        const int q = lane >> 4, l15 = lane & 15;
        const int pxr = wv * 16 + l15;
        u32x4 Areg[8];
#pragma unroll
        for (int f = 0; f < 8; ++f) Areg[f] = wkf[640 + f * 64 + lane];
        bf16x8 Bf[2];
#pragma unroll
        for (int ks = 0; ks < 2; ++ks) {
            u32x4 u;
#pragma unroll
            for (int j = 0; j < 4; ++j)
                u[j] = h2p[(ks * 16 + q * 4 + j) * 68 + pxr];
            Bf[ks] = __builtin_bit_cast(bf16x8, u);
        }
        f32x4 acc[9];
#pragma unroll
        for (int mt = 0; mt < 9; ++mt) acc[mt] = (f32x4){0.f, 0.f, 0.f, 0.f};
#pragma unroll
        for (int mt = 0; mt < 5; ++mt) {
            bf16x8 a0 = __builtin_bit_cast(bf16x8, afragL[(mt * 2 + 0) * 64 + lane]);
            acc[mt] = __builtin_amdgcn_mfma_f32_16x16x32_bf16(a0, Bf[0], acc[mt], 0, 0, 0);
            bf16x8 a1 = __builtin_bit_cast(bf16x8, afragL[(mt * 2 + 1) * 64 + lane]);
            acc[mt] = __builtin_amdgcn_mfma_f32_16x16x32_bf16(a1, Bf[1], acc[mt], 0, 0, 0);
        }
#pragma unroll
        for (int mt = 5; mt < 9; ++mt) {
            acc[mt] = __builtin_amdgcn_mfma_f32_16x16x32_bf16(
                __builtin_bit_cast(bf16x8, Areg[(mt - 5) * 2 + 0]), Bf[0], acc[mt], 0, 0, 0);
            acc[mt] = __builtin_amdgcn_mfma_f32_16x16x32_bf16(
                __builtin_bit_cast(bf16x8, Areg[(mt - 5) * 2 + 1]), Bf[1], acc[mt], 0, 0, 0);
        }
        __syncthreads();                               // h2p reads done

        // ---- Phase D: kv + bk -> kvt; prefetch x taps for cc=0 ----
        float4 xq[2][3]; float xev[2][3];
        {
            const float* xc = x + planeB + ((size_t)c0 << 16);
#pragma unroll
            for (int dy = 0; dy < 3; ++dy) {
                const float* xr = xc + gofs[dy];
                xq[0][dy] = *(const float4*)(xr + gx0);
                if (eact) xev[0][dy] = xr[eoff];
            }
        }
#pragma unroll
        for (int mt = 0; mt < 9; ++mt) {
            int kc0 = 16 * mt + q * 4;
#pragma unroll
            for (int r = 0; r < 4; ++r) {
                float v = acc[mt][r] + bks[kc0 + r];
                kvt[(kc0 + r) * 68 + pxr] = (unsigned short)bf16rne(v);
            }
        }
        __syncthreads();

        // ---- Phase E: apply; x loads rotated one cc ahead ----
#pragma unroll
        for (int cc = 0; cc < 4; ++cc) {
            if (cc < 3) {
                const float* xc = x + planeB + ((size_t)(c0 + cc + 1) << 16);
#pragma unroll
                for (int dy = 0; dy < 3; ++dy) {
                    const float* xr = xc + gofs[dy];
                    xq[(cc + 1) & 1][dy] = *(const float4*)(xr + gx0);
                    if (eact) xev[(cc + 1) & 1][dy] = xr[eoff];
                }
            }
            int c  = c0 + cc;
            int r0 = (9 * c) >> 2;                     // (9c)&3 == cc
            ush4 kr0 = *(const ush4*)&kvt[(r0 + 0) * 68 + px0l];
            ush4 kr1 = *(const ush4*)&kvt[(r0 + 1) * 68 + px0l];
            ush4 kr2 = *(const ush4*)&kvt[(r0 + 2) * 68 + px0l];
            float kvf[3][4];
#pragma unroll
            for (int p = 0; p < 4; ++p) {
                kvf[0][p] = bf2f(kr0[p]);
                kvf[1][p] = bf2f(kr1[p]);
                kvf[2][p] = bf2f(kr2[p]);
            }
            float o[4] = {0.f, 0.f, 0.f, 0.f};
#pragma unroll
            for (int dy = 0; dy < 3; ++dy) {
                float4 xv = xq[cc & 1][dy];
                float inI0 = __shfl_up(xv.w, 1);
                float inI5 = __shfl_down(xv.x, 1);
                if (rowok[dy]) {
                    float in[6];
                    in[0] = eL ? xev[cc & 1][dy] * mL : inI0;
                    in[1] = xv.x; in[2] = xv.y; in[3] = xv.z; in[4] = xv.w;
                    in[5] = eR ? xev[cc & 1][dy] * mR : inI5;
#pragma unroll
                    for (int tx = 0; tx < 3; ++tx) {
#pragma unroll
                        for (int p = 0; p < 4; ++p)
                            o[p] = fmaf(in[p + tx],
                                        kvf[(cc + dy * 3 + tx) >> 2][p], o[p]);
                    }
                }
            }
            float4 o4 = {o[0], o[1], o[2], o[3]};
            *(float4*)(out + planeB + ((size_t)c << 16) + (hrow << 8) + gx0) = o4;
        }
    }
}

// ---------------------------------------------------------------------------
// Fallback (ws too small for wkf): R6-style kernel. LDS 30,272 B.
// ---------------------------------------------------------------------------
__global__ __launch_bounds__(256, 5) void k_fused_fb(const float* __restrict__ x,
        const unsigned short* __restrict__ h1,
        const float* __restrict__ w2, const float* __restrict__ b2,
        const float* __restrict__ wk, const float* __restrict__ bk,
        float* __restrict__ out) {
    extern __shared__ char smem[];
    u32x4*    afrag = (u32x4*)smem;
    uint32_t* h2p   = (uint32_t*)(smem + 18432);
    float*    w2s   = (float*)(smem + 27136);
    float*    b2s   = (float*)(smem + 29440);
    float*    bks   = (float*)(smem + 29696);
    unsigned short* kvt = (unsigned short*)smem;

    const int t = threadIdx.x;
    int bid = blockIdx.x;
    bid = (bid & 7) * 512 + (bid >> 3);
    const int b    = bid >> 10;
    const int rem  = bid & 1023;
    const int hrow = rem >> 2;
    const int w0   = (rem & 3) << 6;
    const size_t planeB = ((size_t)(b * C_)) << 16;

    const int lane = t & 63, wv = t >> 6;
    const int csub = lane >> 4, pg = lane & 15;
    const int px0l = pg << 2;
    const int gx0  = w0 + px0l;
    const int c0   = wv * 16 + csub * 4;

    const int   gxm = (gx0 == 0) ? 0 : gx0 - 1;
    const float mL  = (gx0 == 0) ? 0.f : 1.f;
    const int   gxp = (gx0 + 4 > 255) ? 255 : gx0 + 4;
    const float mR  = (gx0 + 4 > 255) ? 0.f : 1.f;

    bool rowok[3]; int gofs[3];
#pragma unroll
    for (int dy = 0; dy < 3; ++dy) {
        int gy = hrow + dy - 1;
        rowok[dy] = ((unsigned)gy < 256u);
        int gyc = gy < 0 ? 0 : (gy > 255 ? 255 : gy);
        gofs[dy] = gyc << 8;
    }

#pragma unroll
    for (int it = 0; it < 5; ++it) {
        int s = it * 256 + t;
        if (s < 1152) {
            int ln = s & 63;
            int kc = 16 * (s >> 7) + (ln & 15);
            int cb = ((s >> 6) & 1) * 32 + (ln >> 4) * 8;
            const float* wp = wk + kc * 64 + cb;
            float4 f0 = *(const float4*)wp;
            float4 f1 = *(const float4*)(wp + 4);
            u32x4 u; u.x = packbf(f0.x, f0.y); u.y = packbf(f0.z, f0.w);
            u.z = packbf(f1.x, f1.y); u.w = packbf(f1.z, f1.w);
            afrag[s] = u;
        }
    }
#pragma unroll
    for (int it = 0; it < 3; ++it) {
        int s = it * 256 + t;
        if (s < 576) w2s[s] = w2[s];
    }
    if (t < 64)  b2s[t] = b2[t];
    if (t < 144) bks[t] = bk[t];
    __syncthreads();

    float ah[4][4];
#pragma unroll
    for (int cc = 0; cc < 4; ++cc) {
        int c = c0 + cc;
        const unsigned short* hc = h1 + planeB + ((size_t)c << 16);
        float bv = b2s[c];
        float a0 = bv, a1 = bv, a2 = bv, a3 = bv;
#pragma unroll
        for (int dy = 0; dy < 3; ++dy) {
            if (rowok[dy]) {
                const unsigned short* hr = hc + gofs[dy];
                ush4 v = *(const ush4*)(hr + gx0);
                float f0 = bf2f(v[0]), f1 = bf2f(v[1]);
                float f2 = bf2f(v[2]), f3 = bf2f(v[3]);
                float fm = bf2f(hr[gxm]) * mL;
                float fp = bf2f(hr[gxp]) * mR;
                float wL = w2s[c * 9 + dy * 3 + 0];
                float wC = w2s[c * 9 + dy * 3 + 1];
                float wR = w2s[c * 9 + dy * 3 + 2];
                a0 = fmaf(fm, wL, fmaf(f0, wC, fmaf(f1, wR, a0)));
                a1 = fmaf(f0, wL, fmaf(f1, wC, fmaf(f2, wR, a1)));
                a2 = fmaf(f1, wL, fmaf(f2, wC, fmaf(f3, wR, a2)));
                a3 = fmaf(f2, wL, fmaf(f3, wC, fmaf(fp, wR, a3)));
            }
        }
        ah[cc][0] = a0; ah[cc][1] = a1; ah[cc][2] = a2; ah[cc][3] = a3;
    }
    {
        int cpb = c0 >> 1;
        u32x4 u0, u1;
#pragma unroll
        for (int p = 0; p < 4; ++p) {
            u0[p] = packbf(ah[0][p], ah[1][p]);
            u1[p] = packbf(ah[2][p], ah[3][p]);
        }
        *(u32x4*)&h2p[(cpb + 0) * 68 + px0l] = u0;
        *(u32x4*)&h2p[(cpb + 1) * 68 + px0l] = u1;
    }
    __syncthreads();

    const int q = lane >> 4, l15 = lane & 15;
    const int pxr = wv * 16 + l15;
    bf16x8 Bf[2];
#pragma unroll
    for (int ks = 0; ks < 2; ++ks) {
        u32x4 u;
#pragma unroll
        for (int j = 0; j < 4; ++j)
            u[j] = h2p[(ks * 16 + q * 4 + j) * 68 + pxr];
        Bf[ks] = __builtin_bit_cast(bf16x8, u);
    }
    f32x4 acc[9];
#pragma unroll
    for (int mt = 0; mt < 9; ++mt) acc[mt] = (f32x4){0.f, 0.f, 0.f, 0.f};
#pragma unroll
    for (int mt = 0; mt < 9; ++mt) {
        bf16x8 a0 = __builtin_bit_cast(bf16x8, afrag[(mt * 2 + 0) * 64 + lane]);
        acc[mt] = __builtin_amdgcn_mfma_f32_16x16x32_bf16(a0, Bf[0], acc[mt], 0, 0, 0);
        bf16x8 a1 = __builtin_bit_cast(bf16x8, afrag[(mt * 2 + 1) * 64 + lane]);
        acc[mt] = __builtin_amdgcn_mfma_f32_16x16x32_bf16(a1, Bf[1], acc[mt], 0, 0, 0);
    }
    __syncthreads();

#pragma unroll
    for (int mt = 0; mt < 9; ++mt) {
        int kc0 = 16 * mt + q * 4;
#pragma unroll
        for (int r = 0; r < 4; ++r) {
            float v = acc[mt][r] + bks[kc0 + r];
            kvt[(kc0 + r) * 68 + pxr] = (unsigned short)bf16rne(v);
        }
    }
    __syncthreads();

#pragma unroll
    for (int cc = 0; cc < 4; ++cc) {
        int c  = c0 + cc;
        int r0 = (9 * c) >> 2;
        ush4 kr0 = *(const ush4*)&kvt[(r0 + 0) * 68 + px0l];
        ush4 kr1 = *(const ush4*)&kvt[(r0 + 1) * 68 + px0l];
        ush4 kr2 = *(const ush4*)&kvt[(r0 + 2) * 68 + px0l];
        float kvf[3][4];
#pragma unroll
        for (int p = 0; p < 4; ++p) {
            kvf[0][p] = bf2f(kr0[p]);
            kvf[1][p] = bf2f(kr1[p]);
            kvf[2][p] = bf2f(kr2[p]);
        }
        const float* xc = x + planeB + ((size_t)c << 16);
        float o[4] = {0.f, 0.f, 0.f, 0.f};
#pragma unroll
        for (int dy = 0; dy < 3; ++dy) {
            if (rowok[dy]) {
                const float* xr = xc + gofs[dy];
                float4 xv = *(const float4*)(xr + gx0);
                float in[6];
                in[0] = xr[gxm] * mL;
                in[1] = xv.x; in[2] = xv.y; in[3] = xv.z; in[4] = xv.w;
                in[5] = xr[gxp] * mR;
#pragma unroll
                for (int tx = 0; tx < 3; ++tx) {
#pragma unroll
                    for (int p = 0; p < 4; ++p)
                        o[p] = fmaf(in[p + tx],
                                    kvf[(cc + dy * 3 + tx) >> 2][p], o[p]);
                }
            }
        }
        float4 o4 = {o[0], o[1], o[2], o[3]};
        *(float4*)(out + planeB + ((size_t)c << 16) + (hrow << 8) + gx0) = o4;
    }
}

// ---------------------------------------------------------------------------
extern "C" void kernel_launch(void* const* d_in, const int* in_sizes, int n_in,
                              void* d_out, int out_size, void* d_ws, size_t ws_size,
                              hipStream_t stream) {
    const float* x  = (const float*)d_in[0];
    const float* w1 = (const float*)d_in[1];
    const float* b1 = (const float*)d_in[2];
    const float* w2 = (const float*)d_in[3];
    const float* b2 = (const float*)d_in[4];
    const float* wk = (const float*)d_in[5];
    const float* bk = (const float*)d_in[6];
    float* out = (float*)d_out;
    unsigned short* h1 = (unsigned short*)d_ws;      // 32 MB bf16

    const size_t need = (size_t)WS_H1_BYTES + WKF_FRAGS * sizeof(u32x4);
    if (ws_size >= need) {
        u32x4* wkf = (u32x4*)((char*)d_ws + WS_H1_BYTES);
        k_pack<<<(WKF_FRAGS + 255) / 256, 256, 0, stream>>>(wk, wkf);
        k_conv1<<<1024, 256, 0, stream>>>(x, w1, b1, h1);
        k_fused_pre<<<2048, 256, 32960, stream>>>(x, h1, wkf, w2, b2, bk, out);
    } else {
        k_conv1<<<1024, 256, 0, stream>>>(x, w1, b1, h1);
        k_fused_fb<<<4096, 256, 30272, stream>>>(x, h1, w2, b2, wk, bk, out);
    }
}

// Round 16
// 70.651 us; speedup vs baseline: 3.0897x; 1.6289x over previous
//
#include <hip/hip_runtime.h>
#include <hip/hip_bf16.h>
#include <stdint.h>

#define C_ 64
#define WS_H1_BYTES 33554432u          // 32 MB bf16 h1
#define WKF_FRAGS 1152                 // s = (mt*2+ks)*64 + lane

typedef __bf16   bf16x8 __attribute__((ext_vector_type(8)));
typedef float    f32x4  __attribute__((ext_vector_type(4)));
typedef uint32_t u32x4  __attribute__((ext_vector_type(4)));
typedef unsigned short ush4 __attribute__((ext_vector_type(4)));
typedef unsigned short ush8 __attribute__((ext_vector_type(8)));

__device__ __forceinline__ uint32_t bf16rne(float f) {
    uint32_t u = __float_as_uint(f);
    return (u + 0x7fffu + ((u >> 16) & 1u)) >> 16;
}
__device__ __forceinline__ uint32_t packbf(float lo, float hi) {
    return bf16rne(lo) | (bf16rne(hi) << 16);
}
__device__ __forceinline__ float bf2f(uint32_t bits16) {
    return __uint_as_float(bits16 << 16);
}

// ---------------------------------------------------------------------------
// K1: conv1 via MFMA (~HBM roofline, ~15 us).
// ---------------------------------------------------------------------------
__global__ __launch_bounds__(256, 4) void k_conv1(const float* __restrict__ x,
                                                  const float* __restrict__ w1,
                                                  const float* __restrict__ b1,
                                                  unsigned short* __restrict__ h1) {
    __shared__ u32x4 afrag[512];
    const int t = threadIdx.x;
#pragma unroll
    for (int it = 0; it < 2; ++it) {
        int s  = it * 256 + t;
        int ln = s & 63;
        int o  = 16 * (s >> 7) + (ln & 15);
        int c0 = ((s >> 6) & 1) * 32 + (ln >> 4) * 8;
        const float* wp = w1 + o * 64 + c0;
        float4 f0 = *(const float4*)wp;
        float4 f1 = *(const float4*)(wp + 4);
        u32x4 u; u.x = packbf(f0.x, f0.y); u.y = packbf(f0.z, f0.w);
        u.z = packbf(f1.x, f1.y); u.w = packbf(f1.z, f1.w);
        afrag[s] = u;
    }
    __syncthreads();

    const int lane = t & 63, wv = t >> 6;
    const int q = lane >> 4, l15 = lane & 15;
    const int bid = blockIdx.x;
    const int b   = bid >> 8;
    const int px0 = ((bid & 255) << 8) + wv * 64;
    const size_t planeB = ((size_t)(b * C_)) << 16;

    bf16x8 A[4][2];
#pragma unroll
    for (int mt = 0; mt < 4; ++mt)
#pragma unroll
        for (int ks = 0; ks < 2; ++ks)
            A[mt][ks] = __builtin_bit_cast(bf16x8, afrag[(mt * 2 + ks) * 64 + lane]);

    float b1v[4][4];
#pragma unroll
    for (int mt = 0; mt < 4; ++mt)
#pragma unroll
        for (int r = 0; r < 4; ++r) b1v[mt][r] = b1[16 * mt + q * 4 + r];

#pragma unroll
    for (int nt = 0; nt < 4; ++nt) {
        int px = px0 + nt * 16 + l15;
        bf16x8 Bf[2];
#pragma unroll
        for (int ks = 0; ks < 2; ++ks) {
            const float* xp = x + planeB + (((size_t)(ks * 32 + q * 8)) << 16) + px;
            float v[8];
#pragma unroll
            for (int e = 0; e < 8; ++e) v[e] = xp[(size_t)e << 16];
            u32x4 u; u.x = packbf(v[0], v[1]); u.y = packbf(v[2], v[3]);
            u.z = packbf(v[4], v[5]); u.w = packbf(v[6], v[7]);
            Bf[ks] = __builtin_bit_cast(bf16x8, u);
        }
#pragma unroll
        for (int mt = 0; mt < 4; ++mt) {
            f32x4 acc = {0.f, 0.f, 0.f, 0.f};
            acc = __builtin_amdgcn_mfma_f32_16x16x32_bf16(A[mt][0], Bf[0], acc, 0, 0, 0);
            acc = __builtin_amdgcn_mfma_f32_16x16x32_bf16(A[mt][1], Bf[1], acc, 0, 0, 0);
#pragma unroll
            for (int r = 0; r < 4; ++r) {
                int o = 16 * mt + q * 4 + r;
                h1[planeB + (((size_t)o) << 16) + px] =
                    (unsigned short)bf16rne(acc[r] + b1v[mt][r]);
            }
        }
    }
}

// ---------------------------------------------------------------------------
// k_pack: pre-pack wk into bf16 MFMA A-fragments, once. Idempotent.
// ---------------------------------------------------------------------------
__global__ __launch_bounds__(256) void k_pack(const float* __restrict__ wk,
                                              u32x4* __restrict__ wkf) {
    int s = blockIdx.x * 256 + threadIdx.x;
    if (s < WKF_FRAGS) {
        int ln = s & 63;
        int kc = 16 * (s >> 7) + (ln & 15);
        int cb = ((s >> 6) & 1) * 32 + (ln >> 4) * 8;
        const float* wp = wk + kc * 64 + cb;
        float4 f0 = *(const float4*)wp;
        float4 f1 = *(const float4*)(wp + 4);
        u32x4 u; u.x = packbf(f0.x, f0.y); u.y = packbf(f0.z, f0.w);
        u.z = packbf(f1.x, f1.y); u.w = packbf(f1.z, f1.w);
        wkf[s] = u;
    }
}

// ---------------------------------------------------------------------------
// K2 (R13, best validated): Phase B 2ch x 8px (6 ush8 loads), shuffled edge
// taps, mt0-4 A-frags from LDS, mt5-8 streamed from pre-packed global wkf.
// LDS 22,720 B, lb(256,6):
//   afragL : u32x4[640]             0 .. 10,240  (wk frags mt=0..4)
//   h2p    : u32 [32][68]      10,240 .. 18,944
//   kvt    : u16 [144][68]  alias @0 .. 19,584
//   w2s/b2s/bks                19,584 .. 22,720
// ---------------------------------------------------------------------------
__global__ __launch_bounds__(256, 6) void k_fused_pre(const float* __restrict__ x,
        const unsigned short* __restrict__ h1, const u32x4* __restrict__ wkf,
        const float* __restrict__ w2, const float* __restrict__ b2,
        const float* __restrict__ bk, float* __restrict__ out) {
    extern __shared__ char smem[];
    u32x4*    afragL = (u32x4*)smem;                 // [640]
    uint32_t* h2p    = (uint32_t*)(smem + 10240);    // [32][68]
    unsigned short* kvt = (unsigned short*)smem;     // [144][68] alias
    float* w2s = (float*)(smem + 19584);
    float* b2s = (float*)(smem + 21888);
    float* bks = (float*)(smem + 22144);

    const int t = threadIdx.x;
    int bid = blockIdx.x;
    bid = (bid & 7) * 512 + (bid >> 3);              // XCD swizzle (4096%8==0)
    const int b    = bid >> 10;
    const int rem  = bid & 1023;
    const int hrow = rem >> 2;
    const int w0   = (rem & 3) << 6;
    const size_t planeB = ((size_t)(b * C_)) << 16;

    const int lane = t & 63, wv = t >> 6;

    // ---- Phase B thread mapping: 2 ch x 8 px ----
    const int oct  = lane & 7;                       // px octet 0..7
    const int cpw  = lane >> 3;                      // ch-pair within wave 0..7
    const int cpb  = wv * 8 + cpw;                   // global ch-pair 0..31
    const int cB0  = cpb * 2;                        // even channel
    const int pxB  = oct << 3;                       // 0..56 local px
    const int gxB  = w0 + pxB;
    const bool beL = (oct == 0);
    const bool beR = (oct == 7);
    const bool beact = beL | beR;
    const int   bgxm = (gxB == 0) ? 0 : gxB - 1;
    const float bmL  = (gxB == 0) ? 0.f : 1.f;
    const int   bgxp = (gxB + 8 > 255) ? 255 : gxB + 8;
    const float bmR  = (gxB + 8 > 255) ? 0.f : 1.f;
    const int   beoff = beL ? bgxm : bgxp;

    // ---- Phase E thread mapping: 4 ch x 4 px ----
    const int csub = lane >> 4, pg = lane & 15;
    const int px0l = pg << 2;
    const int gx0  = w0 + px0l;
    const int c0   = wv * 16 + csub * 4;
    const bool eL  = (pg == 0);
    const bool eR  = (pg == 15);
    const bool eact = eL | eR;
    const int   gxm = (gx0 == 0) ? 0 : gx0 - 1;
    const float mL  = (gx0 == 0) ? 0.f : 1.f;
    const int   gxp = (gx0 + 4 > 255) ? 255 : gx0 + 4;
    const float mR  = (gx0 + 4 > 255) ? 0.f : 1.f;
    const int   eoff = eL ? gxm : gxp;

    bool rowok[3]; int gofs[3];
#pragma unroll
    for (int dy = 0; dy < 3; ++dy) {
        int gy = hrow + dy - 1;
        rowok[dy] = ((unsigned)gy < 256u);
        int gyc = gy < 0 ? 0 : (gy > 255 ? 255 : gy);
        gofs[dy] = gyc << 8;
    }

    // ---- prefetch ALL Phase-B h1 taps: 6 ush8 + 6 masked edges ----
    ush8 hq[6]; unsigned short hev[6];
#pragma unroll
    for (int cc = 0; cc < 2; ++cc) {
        const unsigned short* hc = h1 + planeB + ((size_t)(cB0 + cc) << 16);
#pragma unroll
        for (int dy = 0; dy < 3; ++dy) {
            const unsigned short* hr = hc + gofs[dy];
            hq[cc * 3 + dy] = *(const ush8*)(hr + gxB);
            if (beact) hev[cc * 3 + dy] = hr[beoff]; // 16/64 lanes active
        }
    }

    // ---- Phase A: stage afragL + weights ----
#pragma unroll
    for (int it = 0; it < 3; ++it) {
        int s = it * 256 + t;
        if (s < 640) afragL[s] = wkf[s];
    }
#pragma unroll
    for (int it = 0; it < 3; ++it) {
        int s = it * 256 + t;
        if (s < 576) w2s[s] = w2[s];
    }
    if (t < 64)  b2s[t] = b2[t];
    if (t < 144) bks[t] = bk[t];
    __syncthreads();

    // ---- Phase B: dw 3x3, 2 ch x 8 px; shuffled edges ----
    float a[2][8];
#pragma unroll
    for (int cc = 0; cc < 2; ++cc) {
        int c = cB0 + cc;
        float bv = b2s[c];
#pragma unroll
        for (int p = 0; p < 8; ++p) a[cc][p] = bv;
#pragma unroll
        for (int dy = 0; dy < 3; ++dy) {
            ush8 v = hq[cc * 3 + dy];
            float f[8];
#pragma unroll
            for (int p = 0; p < 8; ++p) f[p] = bf2f(v[p]);
            float fmI = __shfl_up(f[7], 1);          // uniform control flow
            float fpI = __shfl_down(f[0], 1);
            if (rowok[dy]) {                         // block-uniform branch
                float in[10];
                in[0] = beL ? bf2f(hev[cc * 3 + dy]) * bmL : fmI;
#pragma unroll
                for (int p = 0; p < 8; ++p) in[p + 1] = f[p];
                in[9] = beR ? bf2f(hev[cc * 3 + dy]) * bmR : fpI;
                float wL = w2s[c * 9 + dy * 3 + 0];
                float wC = w2s[c * 9 + dy * 3 + 1];
                float wR = w2s[c * 9 + dy * 3 + 2];
#pragma unroll
                for (int p = 0; p < 8; ++p)
                    a[cc][p] = fmaf(in[p], wL,
                               fmaf(in[p + 1], wC,
                               fmaf(in[p + 2], wR, a[cc][p])));
            }
        }
    }
    {   // h2 bf16 c-pairs: thread owns ch-pair cpb x 8 px -> 2 u32x4 writes
        u32x4 u0, u1;
#pragma unroll
        for (int p = 0; p < 4; ++p) {
            u0[p] = packbf(a[0][p],     a[1][p]);
            u1[p] = packbf(a[0][p + 4], a[1][p + 4]);
        }
        *(u32x4*)&h2p[cpb * 68 + pxB]     = u0;
        *(u32x4*)&h2p[cpb * 68 + pxB + 4] = u1;
    }
    __syncthreads();

    // ---- Phase C: MFMA. mt0-4 from LDS; mt5-8 streamed from wkf ----
    const int q = lane >> 4, l15 = lane & 15;
    const int pxr = wv * 16 + l15;
    u32x4 Areg[8];
#pragma unroll
    for (int f = 0; f < 8; ++f) Areg[f] = wkf[640 + f * 64 + lane];
    bf16x8 Bf[2];
#pragma unroll
    for (int ks = 0; ks < 2; ++ks) {
        u32x4 u;
#pragma unroll
        for (int j = 0; j < 4; ++j)
            u[j] = h2p[(ks * 16 + q * 4 + j) * 68 + pxr];
        Bf[ks] = __builtin_bit_cast(bf16x8, u);
    }
    f32x4 acc[9];
#pragma unroll
    for (int mt = 0; mt < 9; ++mt) acc[mt] = (f32x4){0.f, 0.f, 0.f, 0.f};
#pragma unroll
    for (int mt = 0; mt < 5; ++mt) {
        bf16x8 a0 = __builtin_bit_cast(bf16x8, afragL[(mt * 2 + 0) * 64 + lane]);
        acc[mt] = __builtin_amdgcn_mfma_f32_16x16x32_bf16(a0, Bf[0], acc[mt], 0, 0, 0);
        bf16x8 a1 = __builtin_bit_cast(bf16x8, afragL[(mt * 2 + 1) * 64 + lane]);
        acc[mt] = __builtin_amdgcn_mfma_f32_16x16x32_bf16(a1, Bf[1], acc[mt], 0, 0, 0);
    }
#pragma unroll
    for (int mt = 5; mt < 9; ++mt) {
        acc[mt] = __builtin_amdgcn_mfma_f32_16x16x32_bf16(
            __builtin_bit_cast(bf16x8, Areg[(mt - 5) * 2 + 0]), Bf[0], acc[mt], 0, 0, 0);
        acc[mt] = __builtin_amdgcn_mfma_f32_16x16x32_bf16(
            __builtin_bit_cast(bf16x8, Areg[(mt - 5) * 2 + 1]), Bf[1], acc[mt], 0, 0, 0);
    }
    __syncthreads();                                 // afragL + h2p now dead

    // ---- Phase D: kv + bk -> kvt; prefetch x taps for cc=0 ----
    float4 xq[2][3]; float xev[2][3];
    {
        const float* xc = x + planeB + ((size_t)c0 << 16);
#pragma unroll
        for (int dy = 0; dy < 3; ++dy) {
            const float* xr = xc + gofs[dy];
            xq[0][dy] = *(const float4*)(xr + gx0);
            if (eact) xev[0][dy] = xr[eoff];
        }
    }
#pragma unroll
    for (int mt = 0; mt < 9; ++mt) {
        int kc0 = 16 * mt + q * 4;
#pragma unroll
        for (int r = 0; r < 4; ++r) {
            float v = acc[mt][r] + bks[kc0 + r];
            kvt[(kc0 + r) * 68 + pxr] = (unsigned short)bf16rne(v);
        }
    }
    __syncthreads();

    // ---- Phase E: apply, x loads rotated one cc ahead, shuffled edges ----
#pragma unroll
    for (int cc = 0; cc < 4; ++cc) {
        if (cc < 3) {                                // prefetch next cc
            const float* xc = x + planeB + ((size_t)(c0 + cc + 1) << 16);
#pragma unroll
            for (int dy = 0; dy < 3; ++dy) {
                const float* xr = xc + gofs[dy];
                xq[(cc + 1) & 1][dy] = *(const float4*)(xr + gx0);
                if (eact) xev[(cc + 1) & 1][dy] = xr[eoff];
            }
        }
        int c  = c0 + cc;
        int r0 = (9 * c) >> 2;                       // (9c)&3 == cc
        ush4 kr0 = *(const ush4*)&kvt[(r0 + 0) * 68 + px0l];
        ush4 kr1 = *(const ush4*)&kvt[(r0 + 1) * 68 + px0l];
        ush4 kr2 = *(const ush4*)&kvt[(r0 + 2) * 68 + px0l];
        float kvf[3][4];
#pragma unroll
        for (int p = 0; p < 4; ++p) {
            kvf[0][p] = bf2f(kr0[p]);
            kvf[1][p] = bf2f(kr1[p]);
            kvf[2][p] = bf2f(kr2[p]);
        }
        float o[4] = {0.f, 0.f, 0.f, 0.f};
#pragma unroll
        for (int dy = 0; dy < 3; ++dy) {
            float4 xv = xq[cc & 1][dy];
            float inI0 = __shfl_up(xv.w, 1);         // uniform control flow
            float inI5 = __shfl_down(xv.x, 1);
            if (rowok[dy]) {                         // block-uniform branch
                float in[6];
                in[0] = eL ? xev[cc & 1][dy] * mL : inI0;
                in[1] = xv.x; in[2] = xv.y; in[3] = xv.z; in[4] = xv.w;
                in[5] = eR ? xev[cc & 1][dy] * mR : inI5;
#pragma unroll
                for (int tx = 0; tx < 3; ++tx) {
#pragma unroll
                    for (int p = 0; p < 4; ++p)
                        o[p] = fmaf(in[p + tx],
                                    kvf[(cc + dy * 3 + tx) >> 2][p], o[p]);
                }
            }
        }
        float4 o4 = {o[0], o[1], o[2], o[3]};
        *(float4*)(out + planeB + ((size_t)c << 16) + (hrow << 8) + gx0) = o4;
    }
}

// ---------------------------------------------------------------------------
// Fallback (ws too small for wkf): R6-style kernel. LDS 30,272 B.
// ---------------------------------------------------------------------------
__global__ __launch_bounds__(256, 5) void k_fused_fb(const float* __restrict__ x,
        const unsigned short* __restrict__ h1,
        const float* __restrict__ w2, const float* __restrict__ b2,
        const float* __restrict__ wk, const float* __restrict__ bk,
        float* __restrict__ out) {
    extern __shared__ char smem[];
    u32x4*    afrag = (u32x4*)smem;
    uint32_t* h2p   = (uint32_t*)(smem + 18432);
    float*    w2s   = (float*)(smem + 27136);
    float*    b2s   = (float*)(smem + 29440);
    float*    bks   = (float*)(smem + 29696);
    unsigned short* kvt = (unsigned short*)smem;

    const int t = threadIdx.x;
    int bid = blockIdx.x;
    bid = (bid & 7) * 512 + (bid >> 3);
    const int b    = bid >> 10;
    const int rem  = bid & 1023;
    const int hrow = rem >> 2;
    const int w0   = (rem & 3) << 6;
    const size_t planeB = ((size_t)(b * C_)) << 16;

    const int lane = t & 63, wv = t >> 6;
    const int csub = lane >> 4, pg = lane & 15;
    const int px0l = pg << 2;
    const int gx0  = w0 + px0l;
    const int c0   = wv * 16 + csub * 4;

    const int   gxm = (gx0 == 0) ? 0 : gx0 - 1;
    const float mL  = (gx0 == 0) ? 0.f : 1.f;
    const int   gxp = (gx0 + 4 > 255) ? 255 : gx0 + 4;
    const float mR  = (gx0 + 4 > 255) ? 0.f : 1.f;

    bool rowok[3]; int gofs[3];
#pragma unroll
    for (int dy = 0; dy < 3; ++dy) {
        int gy = hrow + dy - 1;
        rowok[dy] = ((unsigned)gy < 256u);
        int gyc = gy < 0 ? 0 : (gy > 255 ? 255 : gy);
        gofs[dy] = gyc << 8;
    }

#pragma unroll
    for (int it = 0; it < 5; ++it) {
        int s = it * 256 + t;
        if (s < 1152) {
            int ln = s & 63;
            int kc = 16 * (s >> 7) + (ln & 15);
            int cb = ((s >> 6) & 1) * 32 + (ln >> 4) * 8;
            const float* wp = wk + kc * 64 + cb;
            float4 f0 = *(const float4*)wp;
            float4 f1 = *(const float4*)(wp + 4);
            u32x4 u; u.x = packbf(f0.x, f0.y); u.y = packbf(f0.z, f0.w);
            u.z = packbf(f1.x, f1.y); u.w = packbf(f1.z, f1.w);
            afrag[s] = u;
        }
    }
#pragma unroll
    for (int it = 0; it < 3; ++it) {
        int s = it * 256 + t;
        if (s < 576) w2s[s] = w2[s];
    }
    if (t < 64)  b2s[t] = b2[t];
    if (t < 144) bks[t] = bk[t];
    __syncthreads();

    float ah[4][4];
#pragma unroll
    for (int cc = 0; cc < 4; ++cc) {
        int c = c0 + cc;
        const unsigned short* hc = h1 + planeB + ((size_t)c << 16);
        float bv = b2s[c];
        float a0 = bv, a1 = bv, a2 = bv, a3 = bv;
#pragma unroll
        for (int dy = 0; dy < 3; ++dy) {
            if (rowok[dy]) {
                const unsigned short* hr = hc + gofs[dy];
                ush4 v = *(const ush4*)(hr + gx0);
                float f0 = bf2f(v[0]), f1 = bf2f(v[1]);
                float f2 = bf2f(v[2]), f3 = bf2f(v[3]);
                float fm = bf2f(hr[gxm]) * mL;
                float fp = bf2f(hr[gxp]) * mR;
                float wL = w2s[c * 9 + dy * 3 + 0];
                float wC = w2s[c * 9 + dy * 3 + 1];
                float wR = w2s[c * 9 + dy * 3 + 2];
                a0 = fmaf(fm, wL, fmaf(f0, wC, fmaf(f1, wR, a0)));
                a1 = fmaf(f0, wL, fmaf(f1, wC, fmaf(f2, wR, a1)));
                a2 = fmaf(f1, wL, fmaf(f2, wC, fmaf(f3, wR, a2)));
                a3 = fmaf(f2, wL, fmaf(f3, wC, fmaf(fp, wR, a3)));
            }
        }
        ah[cc][0] = a0; ah[cc][1] = a1; ah[cc][2] = a2; ah[cc][3] = a3;
    }
    {
        int cpb = c0 >> 1;
        u32x4 u0, u1;
#pragma unroll
        for (int p = 0; p < 4; ++p) {
            u0[p] = packbf(ah[0][p], ah[1][p]);
            u1[p] = packbf(ah[2][p], ah[3][p]);
        }
        *(u32x4*)&h2p[(cpb + 0) * 68 + px0l] = u0;
        *(u32x4*)&h2p[(cpb + 1) * 68 + px0l] = u1;
    }
    __syncthreads();

    const int q = lane >> 4, l15 = lane & 15;
    const int pxr = wv * 16 + l15;
    bf16x8 Bf[2];
#pragma unroll
    for (int ks = 0; ks < 2; ++ks) {
        u32x4 u;
#pragma unroll
        for (int j = 0; j < 4; ++j)
            u[j] = h2p[(ks * 16 + q * 4 + j) * 68 + pxr];
        Bf[ks] = __builtin_bit_cast(bf16x8, u);
    }
    f32x4 acc[9];
#pragma unroll
    for (int mt = 0; mt < 9; ++mt) acc[mt] = (f32x4){0.f, 0.f, 0.f, 0.f};
#pragma unroll
    for (int mt = 0; mt < 9; ++mt) {
        bf16x8 a0 = __builtin_bit_cast(bf16x8, afrag[(mt * 2 + 0) * 64 + lane]);
        acc[mt] = __builtin_amdgcn_mfma_f32_16x16x32_bf16(a0, Bf[0], acc[mt], 0, 0, 0);
        bf16x8 a1 = __builtin_bit_cast(bf16x8, afrag[(mt * 2 + 1) * 64 + lane]);
        acc[mt] = __builtin_amdgcn_mfma_f32_16x16x32_bf16(a1, Bf[1], acc[mt], 0, 0, 0);
    }
    __syncthreads();

#pragma unroll
    for (int mt = 0; mt < 9; ++mt) {
        int kc0 = 16 * mt + q * 4;
#pragma unroll
        for (int r = 0; r < 4; ++r) {
            float v = acc[mt][r] + bks[kc0 + r];
            kvt[(kc0 + r) * 68 + pxr] = (unsigned short)bf16rne(v);
        }
    }
    __syncthreads();

#pragma unroll
    for (int cc = 0; cc < 4; ++cc) {
        int c  = c0 + cc;
        int r0 = (9 * c) >> 2;
        ush4 kr0 = *(const ush4*)&kvt[(r0 + 0) * 68 + px0l];
        ush4 kr1 = *(const ush4*)&kvt[(r0 + 1) * 68 + px0l];
        ush4 kr2 = *(const ush4*)&kvt[(r0 + 2) * 68 + px0l];
        float kvf[3][4];
#pragma unroll
        for (int p = 0; p < 4; ++p) {
            kvf[0][p] = bf2f(kr0[p]);
            kvf[1][p] = bf2f(kr1[p]);
            kvf[2][p] = bf2f(kr2[p]);
        }
        const float* xc = x + planeB + ((size_t)c << 16);
        float o[4] = {0.f, 0.f, 0.f, 0.f};
#pragma unroll
        for (int dy = 0; dy < 3; ++dy) {
            if (rowok[dy]) {
                const float* xr = xc + gofs[dy];
                float4 xv = *(const float4*)(xr + gx0);
                float in[6];
                in[0] = xr[gxm] * mL;
                in[1] = xv.x; in[2] = xv.y; in[3] = xv.z; in[4] = xv.w;
                in[5] = xr[gxp] * mR;
#pragma unroll
                for (int tx = 0; tx < 3; ++tx) {
#pragma unroll
                    for (int p = 0; p < 4; ++p)
                        o[p] = fmaf(in[p + tx],
                                    kvf[(cc + dy * 3 + tx) >> 2][p], o[p]);
                }
            }
        }
        float4 o4 = {o[0], o[1], o[2], o[3]};
        *(float4*)(out + planeB + ((size_t)c << 16) + (hrow << 8) + gx0) = o4;
    }
}

// ---------------------------------------------------------------------------
extern "C" void kernel_launch(void* const* d_in, const int* in_sizes, int n_in,
                              void* d_out, int out_size, void* d_ws, size_t ws_size,
                              hipStream_t stream) {
    const float* x  = (const float*)d_in[0];
    const float* w1 = (const float*)d_in[1];
    const float* b1 = (const float*)d_in[2];
    const float* w2 = (const float*)d_in[3];
    const float* b2 = (const float*)d_in[4];
    const float* wk = (const float*)d_in[5];
    const float* bk = (const float*)d_in[6];
    float* out = (float*)d_out;
    unsigned short* h1 = (unsigned short*)d_ws;      // 32 MB bf16

    const size_t need = (size_t)WS_H1_BYTES + WKF_FRAGS * sizeof(u32x4);
    if (ws_size >= need) {
        u32x4* wkf = (u32x4*)((char*)d_ws + WS_H1_BYTES);
        k_pack<<<(WKF_FRAGS + 255) / 256, 256, 0, stream>>>(wk, wkf);
        k_conv1<<<1024, 256, 0, stream>>>(x, w1, b1, h1);
        k_fused_pre<<<4096, 256, 22720, stream>>>(x, h1, wkf, w2, b2, bk, out);
    } else {
        k_conv1<<<1024, 256, 0, stream>>>(x, w1, b1, h1);
        k_fused_fb<<<4096, 256, 30272, stream>>>(x, h1, w2, b2, wk, bk, out);
    }
}